// Round 5
// baseline (180.446 us; speedup 1.0000x reference)
//
#include <hip/hip_runtime.h>
#include <cstdint>
#include <cstddef>

#define B 4096
#define D 128
#define MARGIN_F 0.2f
#define CW 128            // per-wave candidate capacity

typedef short bf16x8 __attribute__((ext_vector_type(8)));
typedef float f32x4 __attribute__((ext_vector_type(4)));

// order-preserving float->uint (ascending uint == ascending float)
__device__ __forceinline__ uint32_t xform_key(float f) {
    uint32_t u = __float_as_uint(f);
    return u ^ (uint32_t)((((int32_t)u) >> 31) | 0x80000000);
}
__device__ __forceinline__ float unxform_key(uint32_t k) {
    uint32_t u = (k & 0x80000000u) ? (k ^ 0x80000000u) : ~k;
    return __uint_as_float(u);
}
__device__ __forceinline__ unsigned short f2bf(float f) {   // round-nearest-even
    uint32_t u = __float_as_uint(f);
    return (unsigned short)((u + 0x7FFFu + ((u >> 16) & 1u)) >> 16);
}
__device__ __forceinline__ bf16x8 load_frag_bf16(const float* p) {
    float4 x = *(const float4*)p;
    float4 y = *(const float4*)(p + 4);
    bf16x8 r;
    r[0] = (short)f2bf(x.x); r[1] = (short)f2bf(x.y);
    r[2] = (short)f2bf(x.z); r[3] = (short)f2bf(x.w);
    r[4] = (short)f2bf(y.x); r[5] = (short)f2bf(y.y);
    r[6] = (short)f2bf(y.z); r[7] = (short)f2bf(y.w);
    return r;
}

// sq[i] = ||R[i]||^2 (fp32); block 0 also zeroes the output scalar
__global__ __launch_bounds__(256) void sq_kernel(const float* __restrict__ R,
                                                 float* __restrict__ sq,
                                                 float* __restrict__ out) {
    if (blockIdx.x == 0 && threadIdx.x == 0) out[0] = 0.0f;
    int wave = threadIdx.x >> 6;
    int lane = threadIdx.x & 63;
    int row  = blockIdx.x * 4 + wave;
    const float2* R2 = (const float2*)R + (size_t)row * (D / 2);
    float2 v = R2[lane];
    float s = v.x * v.x + v.y * v.y;
#pragma unroll
    for (int off = 32; off > 0; off >>= 1) s += __shfl_down(s, off);
    if (lane == 0) sq[row] = s;
}

// bf16-MFMA gram + dist/margin epilogue, writes xformed uint32 keys.
__global__ __launch_bounds__(256) void gemm_sim_mfma(const float* __restrict__ R,
                                                     const float* __restrict__ sq,
                                                     const int* __restrict__ labels,
                                                     uint32_t* __restrict__ simk) {
    const int tid  = threadIdx.x;
    const int wid  = tid >> 6, lane = tid & 63;
    const int q    = lane >> 4, t = lane & 15;
    const int gi0  = blockIdx.y * 128 + (wid >> 1) * 64;
    const int gj0  = blockIdx.x * 128 + (wid & 1) * 64;

    f32x4 acc[4][4];
#pragma unroll
    for (int mi = 0; mi < 4; ++mi)
#pragma unroll
        for (int ni = 0; ni < 4; ++ni) acc[mi][ni] = (f32x4)0.0f;

    const float* baseA = R + (size_t)(gi0 + t) * D + q * 8;
    const float* baseB = R + (size_t)(gj0 + t) * D + q * 8;

#pragma unroll
    for (int kq = 0; kq < 4; ++kq) {
        bf16x8 af[4], bfr[4];
#pragma unroll
        for (int mi = 0; mi < 4; ++mi)
            af[mi] = load_frag_bf16(baseA + (size_t)mi * 16 * D + kq * 32);
#pragma unroll
        for (int ni = 0; ni < 4; ++ni)
            bfr[ni] = load_frag_bf16(baseB + (size_t)ni * 16 * D + kq * 32);
#pragma unroll
        for (int mi = 0; mi < 4; ++mi)
#pragma unroll
            for (int ni = 0; ni < 4; ++ni)
                acc[mi][ni] = __builtin_amdgcn_mfma_f32_16x16x32_bf16(
                    af[mi], bfr[ni], acc[mi][ni], 0, 0, 0);
    }

    float sqc[4]; int lc[4];
#pragma unroll
    for (int ni = 0; ni < 4; ++ni) {
        sqc[ni] = sq[gj0 + ni * 16 + t];
        lc[ni]  = labels[gj0 + ni * 16 + t];
    }
#pragma unroll
    for (int mi = 0; mi < 4; ++mi) {
#pragma unroll
        for (int r = 0; r < 4; ++r) {
            int gr = gi0 + mi * 16 + q * 4 + r;
            float sqr = sq[gr];
            int   lr  = labels[gr];
            uint32_t* dst = simk + (size_t)gr * B + gj0 + t;
#pragma unroll
            for (int ni = 0; ni < 4; ++ni) {
                float g  = acc[mi][ni][r];
                float d2 = fmaxf(sqr + sqc[ni] - 2.0f * g, 0.0f);
                float dist = (d2 > 0.0f) ? sqrtf(d2) : 0.0f;
                float s = -dist + ((lr == lc[ni]) ? 0.0f : MARGIN_F);
                dst[ni * 16] = xform_key(s);
            }
        }
    }
}

// ONE WAVE PER ROW, row keys in a private 16KB LDS strip (NOT registers —
// r4's uv[64] was compiler-demoted to scratch, VGPR_Count=64 proved it).
// Zero __syncthreads until the final per-block combine.
__global__ __launch_bounds__(256) void row_loss_lds(const uint32_t* __restrict__ simk,
                                                    const int* __restrict__ labels,
                                                    float* __restrict__ out) {
    __shared__ uint32_t S[4][B];           // 64 KB: per-wave row strip
    __shared__ uint32_t cand_u[4][CW];
    __shared__ int      cand_m[4][CW];
    __shared__ int      cnt_w[4];
    __shared__ float    wsum[4];

    const int wid  = threadIdx.x >> 6;
    const int lane = threadIdx.x & 63;
    const int row  = blockIdx.x * 4 + wid;
    const int lane4 = lane * 4;

    if (lane == 0) cnt_w[wid] = 0;

    const uint4* pv = (const uint4*)(simk + (size_t)row * B);
    const int4*  lv = (const int4*)labels;
    const int li = labels[row];
    uint4* Sv = (uint4*)S[wid];

    // phase A: stream row -> LDS; per-lane top-2 + match bits in flight.
    // element e (0..63) lives at j = (e>>2)*256 + lane*4 + (e&3)
    uint32_t t1 = 0, t2 = 0;
    uint64_t mbits = 0;
#pragma unroll
    for (int qq = 0; qq < 16; ++qq) {
        uint4 v  = pv[qq * 64 + lane];
        int4  lb = lv[qq * 64 + lane];
        Sv[qq * 64 + lane] = v;
        uint32_t mn;
        mn = min(t1, v.x); t1 = max(t1, v.x); t2 = max(t2, mn);
        mn = min(t1, v.y); t1 = max(t1, v.y); t2 = max(t2, mn);
        mn = min(t1, v.z); t1 = max(t1, v.z); t2 = max(t2, mn);
        mn = min(t1, v.w); t1 = max(t1, v.w); t2 = max(t2, mn);
        mbits |= (uint64_t)(lb.x == li) << (qq * 4 + 0);
        mbits |= (uint64_t)(lb.y == li) << (qq * 4 + 1);
        mbits |= (uint64_t)(lb.z == li) << (qq * 4 + 2);
        mbits |= (uint64_t)(lb.w == li) << (qq * 4 + 3);
    }

    // k = row match count (includes self)
    int kloc = __popcll(mbits);
#pragma unroll
    for (int off = 32; off > 0; off >>= 1) kloc += __shfl_xor(kloc, off);
    const int k = kloc;
    const float kf = (float)k;

    // ballot binary search: T = (k-th largest of the 128-subset) & 0xFFFFFF00
    // subset k-th <= full k-th, so {u>=T} covers the true top-k
    const int kneed = min(k, 128);
    uint32_t cur = 0;
#pragma unroll
    for (int b = 23; b >= 0; --b) {
        uint32_t g = cur | (1u << (b + 8));
        int c = __popcll(__ballot(t1 >= g)) + __popcll(__ballot(t2 >= g));
        if (c >= kneed) cur = g;
    }
    const uint32_t T = cur;

    // phase D: gather candidates = {u >= T} U {matches} from LDS
#pragma unroll
    for (int qq = 0; qq < 16; ++qq) {
        uint4 v = Sv[qq * 64 + lane];
        uint32_t uu[4] = {v.x, v.y, v.z, v.w};
#pragma unroll
        for (int c = 0; c < 4; ++c) {
            int e = qq * 4 + c;
            int m = (int)((mbits >> e) & 1);
            if (uu[c] >= T || m) {
                int p = atomicAdd(&cnt_w[wid], 1);
                if (p < CW) {
                    cand_u[wid][p] = uu[c];
                    cand_m[wid][p] = (qq * 256 + lane4 + c) | (m << 12);
                }
            }
        }
    }
    const int ncand = min(cnt_w[wid], CW);

    float facc = 0.0f;

    // candidate-internal exact ranks for u >= T (all beaters are candidates)
    for (int s = lane; s < ncand; s += 64) {
        uint32_t uc = cand_u[wid][s];
        int meta = cand_m[wid][s];
        int jc = meta & 0xFFF;
        int m  = (meta >> 12) & 1;
        if (uc >= T) {
            int cnt = 0;
            for (int c = 0; c < ncand; ++c) {
                uint32_t u2 = cand_u[wid][c];
                int j2 = cand_m[wid][c] & 0xFFF;
                cnt += (u2 > uc || (u2 == uc && j2 < jc)) ? 1 : 0;
            }
            int rank = 1 + cnt;
            float v = unxform_key(uc);
            if (!m && rank <= k)
                facc += v * (0.5f + ((kf - (float)rank + 1.0f) / kf) * 0.5f);
            else if (m && rank > k)
                facc -= v * (0.5f + (((float)rank - kf) / (float)(B - k)) * 0.5f);
        }
    }

    // below-T matches (definitely fn): exact global rank via LDS strip scan
    for (int c = 0; c < ncand; ++c) {
        uint32_t uc = cand_u[wid][c];   // broadcast read -> wave-uniform branch
        if (uc < T) {
            int jc = cand_m[wid][c] & 0xFFF;
            int cnt = 0;
#pragma unroll
            for (int qq = 0; qq < 16; ++qq) {
                uint4 v = Sv[qq * 64 + lane];
                int jb = qq * 256 + lane4;
                cnt += (v.x > uc || (v.x == uc && jb + 0 < jc)) ? 1 : 0;
                cnt += (v.y > uc || (v.y == uc && jb + 1 < jc)) ? 1 : 0;
                cnt += (v.z > uc || (v.z == uc && jb + 2 < jc)) ? 1 : 0;
                cnt += (v.w > uc || (v.w == uc && jb + 3 < jc)) ? 1 : 0;
            }
#pragma unroll
            for (int off = 32; off > 0; off >>= 1) cnt += __shfl_xor(cnt, off);
            if (lane == 0) {
                int rank = 1 + cnt;
                float v = unxform_key(uc);
                facc -= v * (0.5f + (((float)rank - kf) / (float)(B - k)) * 0.5f);
            }
        }
    }

    // wave sum -> per-block combine -> one atomic per 4 rows
#pragma unroll
    for (int off = 32; off > 0; off >>= 1) facc += __shfl_xor(facc, off);
    if (lane == 0) wsum[wid] = facc;
    __syncthreads();
    if (threadIdx.x == 0)
        atomicAdd(out, wsum[0] + wsum[1] + wsum[2] + wsum[3]);
}

extern "C" void kernel_launch(void* const* d_in, const int* in_sizes, int n_in,
                              void* d_out, int out_size, void* d_ws, size_t ws_size,
                              hipStream_t stream) {
    const float* R      = (const float*)d_in[0];
    const int*   labels = (const int*)d_in[1];
    float* out = (float*)d_out;

    float*    sq   = (float*)d_ws;                       // 4096 floats
    uint32_t* simk = (uint32_t*)d_ws + 4096 + 64;        // 4096*4096 keys (64 MB)

    hipLaunchKernelGGL(sq_kernel, dim3(B / 4), dim3(256), 0, stream, R, sq, out);
    hipLaunchKernelGGL(gemm_sim_mfma, dim3(B / 128, B / 128), dim3(256), 0, stream,
                       R, sq, labels, simk);
    hipLaunchKernelGGL(row_loss_lds, dim3(B / 4), dim3(256), 0, stream, simk, labels, out);
}

// Round 6
// 167.668 us; speedup vs baseline: 1.0762x; 1.0762x over previous
//
#include <hip/hip_runtime.h>
#include <cstdint>
#include <cstddef>

#define B 4096
#define D 128
#define MARGIN_F 0.2f
#define CW 256            // per-wave candidate capacity

typedef short bf16x8 __attribute__((ext_vector_type(8)));
typedef float f32x4 __attribute__((ext_vector_type(4)));

// order-preserving float->uint (ascending uint == ascending float)
__device__ __forceinline__ uint32_t xform_key(float f) {
    uint32_t u = __float_as_uint(f);
    return u ^ (uint32_t)((((int32_t)u) >> 31) | 0x80000000);
}
// decode 16-bit truncated key (bucket center = k16<<16 under round-to-nearest encode)
__device__ __forceinline__ float unxform16(uint32_t k16) {
    uint32_t u = k16 << 16;
    u = (u & 0x80000000u) ? (u ^ 0x80000000u) : ~u;
    return __uint_as_float(u);
}
__device__ __forceinline__ unsigned short f2bf(float f) {   // round-nearest-even
    uint32_t u = __float_as_uint(f);
    return (unsigned short)((u + 0x7FFFu + ((u >> 16) & 1u)) >> 16);
}
__device__ __forceinline__ bf16x8 load_frag_bf16(const float* p) {
    float4 x = *(const float4*)p;
    float4 y = *(const float4*)(p + 4);
    bf16x8 r;
    r[0] = (short)f2bf(x.x); r[1] = (short)f2bf(x.y);
    r[2] = (short)f2bf(x.z); r[3] = (short)f2bf(x.w);
    r[4] = (short)f2bf(y.x); r[5] = (short)f2bf(y.y);
    r[6] = (short)f2bf(y.z); r[7] = (short)f2bf(y.w);
    return r;
}

// sq[i] = ||R[i]||^2 (fp32); block 0 also zeroes the output scalar
__global__ __launch_bounds__(256) void sq_kernel(const float* __restrict__ R,
                                                 float* __restrict__ sq,
                                                 float* __restrict__ out) {
    if (blockIdx.x == 0 && threadIdx.x == 0) out[0] = 0.0f;
    int wave = threadIdx.x >> 6;
    int lane = threadIdx.x & 63;
    int row  = blockIdx.x * 4 + wave;
    const float2* R2 = (const float2*)R + (size_t)row * (D / 2);
    float2 v = R2[lane];
    float s = v.x * v.x + v.y * v.y;
#pragma unroll
    for (int off = 32; off > 0; off >>= 1) s += __shfl_down(s, off);
    if (lane == 0) sq[row] = s;
}

// bf16-MFMA gram + dist/margin epilogue -> 16-bit keys (round-to-nearest)
__global__ __launch_bounds__(256) void gemm_sim_mfma(const float* __restrict__ R,
                                                     const float* __restrict__ sq,
                                                     const int* __restrict__ labels,
                                                     unsigned short* __restrict__ simk) {
    const int tid  = threadIdx.x;
    const int wid  = tid >> 6, lane = tid & 63;
    const int q    = lane >> 4, t = lane & 15;
    const int gi0  = blockIdx.y * 128 + (wid >> 1) * 64;
    const int gj0  = blockIdx.x * 128 + (wid & 1) * 64;

    f32x4 acc[4][4];
#pragma unroll
    for (int mi = 0; mi < 4; ++mi)
#pragma unroll
        for (int ni = 0; ni < 4; ++ni) acc[mi][ni] = (f32x4)0.0f;

    const float* baseA = R + (size_t)(gi0 + t) * D + q * 8;
    const float* baseB = R + (size_t)(gj0 + t) * D + q * 8;

#pragma unroll
    for (int kq = 0; kq < 4; ++kq) {
        bf16x8 af[4], bfr[4];
#pragma unroll
        for (int mi = 0; mi < 4; ++mi)
            af[mi] = load_frag_bf16(baseA + (size_t)mi * 16 * D + kq * 32);
#pragma unroll
        for (int ni = 0; ni < 4; ++ni)
            bfr[ni] = load_frag_bf16(baseB + (size_t)ni * 16 * D + kq * 32);
#pragma unroll
        for (int mi = 0; mi < 4; ++mi)
#pragma unroll
            for (int ni = 0; ni < 4; ++ni)
                acc[mi][ni] = __builtin_amdgcn_mfma_f32_16x16x32_bf16(
                    af[mi], bfr[ni], acc[mi][ni], 0, 0, 0);
    }

    float sqc[4]; int lc[4];
#pragma unroll
    for (int ni = 0; ni < 4; ++ni) {
        sqc[ni] = sq[gj0 + ni * 16 + t];
        lc[ni]  = labels[gj0 + ni * 16 + t];
    }
#pragma unroll
    for (int mi = 0; mi < 4; ++mi) {
#pragma unroll
        for (int r = 0; r < 4; ++r) {
            int gr = gi0 + mi * 16 + q * 4 + r;
            float sqr = sq[gr];
            int   lr  = labels[gr];
            unsigned short* dst = simk + (size_t)gr * B + gj0 + t;
#pragma unroll
            for (int ni = 0; ni < 4; ++ni) {
                float g  = acc[mi][ni][r];
                float d2 = fmaxf(sqr + sqc[ni] - 2.0f * g, 0.0f);
                float dist = (d2 > 0.0f) ? sqrtf(d2) : 0.0f;
                float s = -dist + ((lr == lc[ni]) ? 0.0f : MARGIN_F);
                uint32_t key = xform_key(s);           // sim <= 0.2 -> no overflow on +0x8000
                dst[ni * 16] = (unsigned short)((key + 0x8000u) >> 16);
            }
        }
    }
}

// ONE WAVE PER ROW. 64 16-bit keys/lane packed into 8 uint4 (32 VGPRs) —
// r4's spill came from 64x32-bit unpacked (64 VGPRs); this halves it.
// No LDS row strip; LDS holds only the ~k+slack candidates.
__global__ __launch_bounds__(256) void row_loss16(const unsigned short* __restrict__ simk,
                                                  const int* __restrict__ labels,
                                                  float* __restrict__ out) {
    __shared__ uint32_t cand_u[4][CW];
    __shared__ int      cand_m[4][CW];
    __shared__ int      cnt_w[4];
    __shared__ float    wsum[4];

    const int wid  = threadIdx.x >> 6;
    const int lane = threadIdx.x & 63;
    const int row  = blockIdx.x * 4 + wid;

    if (lane == 0) cnt_w[wid] = 0;   // same-wave DS ordering makes this visible below

    const uint4* pv = (const uint4*)(simk + (size_t)row * B);   // 512 uint4 per row
    const int4*  lv = (const int4*)labels;
    const int li = labels[row];

    // element e = q*8+c lives at j = (q*64+lane)*8 + c
    uint4 kv[8];
    uint64_t mbits = 0;
    uint32_t t1 = 0, t2 = 0;
#pragma unroll
    for (int q = 0; q < 8; ++q) {
        kv[q] = pv[q * 64 + lane];
        const int lb = (q * 64 + lane) * 2;       // int4 index of first 4 labels
        int4 la = lv[lb], lc = lv[lb + 1];
        uint32_t u[8] = {kv[q].x & 0xFFFFu, kv[q].x >> 16,
                         kv[q].y & 0xFFFFu, kv[q].y >> 16,
                         kv[q].z & 0xFFFFu, kv[q].z >> 16,
                         kv[q].w & 0xFFFFu, kv[q].w >> 16};
#pragma unroll
        for (int c = 0; c < 8; ++c) {
            uint32_t mn = min(t1, u[c]);
            t1 = max(t1, u[c]);
            t2 = max(t2, mn);
        }
        mbits |= (uint64_t)(la.x == li) << (q * 8 + 0);
        mbits |= (uint64_t)(la.y == li) << (q * 8 + 1);
        mbits |= (uint64_t)(la.z == li) << (q * 8 + 2);
        mbits |= (uint64_t)(la.w == li) << (q * 8 + 3);
        mbits |= (uint64_t)(lc.x == li) << (q * 8 + 4);
        mbits |= (uint64_t)(lc.y == li) << (q * 8 + 5);
        mbits |= (uint64_t)(lc.z == li) << (q * 8 + 6);
        mbits |= (uint64_t)(lc.w == li) << (q * 8 + 7);
    }

    int kloc = __popcll(mbits);
#pragma unroll
    for (int off = 32; off > 0; off >>= 1) kloc += __shfl_xor(kloc, off);
    const int k = kloc;
    const float kf = (float)k;

    // ballot binary search over 16-bit values: T = exact k-th largest of the
    // 128-subset (per-lane top-2); subset k-th <= full k-th -> {u>=T} covers top-k
    const int kneed = min(k, 128);
    uint32_t T = 0;
#pragma unroll
    for (int b = 15; b >= 0; --b) {
        uint32_t g = T | (1u << b);
        int c = __popcll(__ballot(t1 >= g)) + __popcll(__ballot(t2 >= g));
        if (c >= kneed) T = g;
    }

    // gather candidates = {u >= T} U {matches} straight from registers
#pragma unroll
    for (int q = 0; q < 8; ++q) {
        uint32_t u[8] = {kv[q].x & 0xFFFFu, kv[q].x >> 16,
                         kv[q].y & 0xFFFFu, kv[q].y >> 16,
                         kv[q].z & 0xFFFFu, kv[q].z >> 16,
                         kv[q].w & 0xFFFFu, kv[q].w >> 16};
#pragma unroll
        for (int c = 0; c < 8; ++c) {
            int e = q * 8 + c;
            int m = (int)((mbits >> e) & 1);
            if (u[c] >= T || m) {
                int p = atomicAdd(&cnt_w[wid], 1);
                if (p < CW) {
                    cand_u[wid][p] = u[c];
                    cand_m[wid][p] = ((q * 64 + lane) * 8 + c) | (m << 12);
                }
            }
        }
    }
    const int ncand = min(cnt_w[wid], CW);

    float facc = 0.0f;

    // candidate-internal exact ranks for u >= T (every beater is a candidate)
    for (int s = lane; s < ncand; s += 64) {
        uint32_t uc = cand_u[wid][s];
        int meta = cand_m[wid][s];
        int jc = meta & 0xFFF;
        int m  = (meta >> 12) & 1;
        if (uc >= T) {
            int cnt = 0;
            for (int c = 0; c < ncand; ++c) {
                uint32_t u2 = cand_u[wid][c];
                int j2 = cand_m[wid][c] & 0xFFF;
                cnt += (u2 > uc || (u2 == uc && j2 < jc)) ? 1 : 0;
            }
            int rank = 1 + cnt;
            float v = unxform16(uc);
            if (!m && rank <= k)
                facc += v * (0.5f + ((kf - (float)rank + 1.0f) / kf) * 0.5f);
            else if (m && rank > k)
                facc -= v * (0.5f + (((float)rank - kf) / (float)(B - k)) * 0.5f);
        }
    }

    // below-T matches (rank > k guaranteed): exact global rank from registers
    for (int c = 0; c < ncand; ++c) {
        uint32_t uc = cand_u[wid][c];   // broadcast read -> wave-uniform branch
        if (uc < T) {
            int jc = cand_m[wid][c] & 0xFFF;
            int cnt = 0;
#pragma unroll
            for (int q = 0; q < 8; ++q) {
                uint32_t u[8] = {kv[q].x & 0xFFFFu, kv[q].x >> 16,
                                 kv[q].y & 0xFFFFu, kv[q].y >> 16,
                                 kv[q].z & 0xFFFFu, kv[q].z >> 16,
                                 kv[q].w & 0xFFFFu, kv[q].w >> 16};
                int jb = (q * 64 + lane) * 8;
#pragma unroll
                for (int cc = 0; cc < 8; ++cc)
                    cnt += (u[cc] > uc || (u[cc] == uc && jb + cc < jc)) ? 1 : 0;
            }
#pragma unroll
            for (int off = 32; off > 0; off >>= 1) cnt += __shfl_xor(cnt, off);
            if (lane == 0) {
                int rank = 1 + cnt;
                float v = unxform16(uc);
                facc -= v * (0.5f + (((float)rank - kf) / (float)(B - k)) * 0.5f);
            }
        }
    }

    // wave sum -> per-block combine -> one atomic per 4 rows
#pragma unroll
    for (int off = 32; off > 0; off >>= 1) facc += __shfl_xor(facc, off);
    if (lane == 0) wsum[wid] = facc;
    __syncthreads();
    if (threadIdx.x == 0)
        atomicAdd(out, wsum[0] + wsum[1] + wsum[2] + wsum[3]);
}

extern "C" void kernel_launch(void* const* d_in, const int* in_sizes, int n_in,
                              void* d_out, int out_size, void* d_ws, size_t ws_size,
                              hipStream_t stream) {
    const float* R      = (const float*)d_in[0];
    const int*   labels = (const int*)d_in[1];
    float* out = (float*)d_out;

    float*          sq   = (float*)d_ws;                                   // 16 KB
    unsigned short* simk = (unsigned short*)((char*)d_ws + 16 * 1024 + 256); // 32 MB

    hipLaunchKernelGGL(sq_kernel, dim3(B / 4), dim3(256), 0, stream, R, sq, out);
    hipLaunchKernelGGL(gemm_sim_mfma, dim3(B / 128, B / 128), dim3(256), 0, stream,
                       R, sq, labels, simk);
    hipLaunchKernelGGL(row_loss16, dim3(B / 4), dim3(256), 0, stream, simk, labels, out);
}

// Round 7
// 147.539 us; speedup vs baseline: 1.2230x; 1.1364x over previous
//
#include <hip/hip_runtime.h>
#include <cstdint>
#include <cstddef>

#define B 4096
#define D 128
#define MARGIN_F 0.2f
#define CW 256            // per-wave candidate capacity (row_loss)

typedef short bf16x8 __attribute__((ext_vector_type(8)));
typedef float f32x4 __attribute__((ext_vector_type(4)));

// order-preserving float->uint (ascending uint == ascending float)
__device__ __forceinline__ uint32_t xform_key(float f) {
    uint32_t u = __float_as_uint(f);
    return u ^ (uint32_t)((((int32_t)u) >> 31) | 0x80000000);
}
// decode 16-bit truncated key (bucket center under round-to-nearest encode)
__device__ __forceinline__ float unxform16(uint32_t k16) {
    uint32_t u = k16 << 16;
    u = (u & 0x80000000u) ? (u ^ 0x80000000u) : ~u;
    return __uint_as_float(u);
}
__device__ __forceinline__ unsigned short f2bf(float f) {   // round-nearest-even
    uint32_t u = __float_as_uint(f);
    return (unsigned short)((u + 0x7FFFu + ((u >> 16) & 1u)) >> 16);
}

// sq[i] = ||R[i]||^2 (fp32); block 0 also zeroes the output scalar
__global__ __launch_bounds__(256) void sq_kernel(const float* __restrict__ R,
                                                 float* __restrict__ sq,
                                                 float* __restrict__ out) {
    if (blockIdx.x == 0 && threadIdx.x == 0) out[0] = 0.0f;
    int wave = threadIdx.x >> 6;
    int lane = threadIdx.x & 63;
    int row  = blockIdx.x * 4 + wave;
    const float2* R2 = (const float2*)R + (size_t)row * (D / 2);
    float2 v = R2[lane];
    float s = v.x * v.x + v.y * v.y;
#pragma unroll
    for (int off = 32; off > 0; off >>= 1) s += __shfl_down(s, off);
    if (lane == 0) sq[row] = s;
}

// R (fp32) -> Rb (bf16 rne), row-major 4096x128
__global__ __launch_bounds__(256) void conv_kernel(const float* __restrict__ R,
                                                   unsigned short* __restrict__ Rb) {
    int idx = (blockIdx.x * 256 + threadIdx.x) * 4;
    float4 v = *(const float4*)(R + idx);
    ushort4 o;
    o.x = f2bf(v.x); o.y = f2bf(v.y); o.z = f2bf(v.z); o.w = f2bf(v.w);
    *(ushort4*)(Rb + idx) = o;
}

// LDS-staged bf16 MFMA gram + dist/margin epilogue -> 16-bit keys.
// Stage both 128x128 bf16 tiles (64KB) once (K=128 fits); XOR chunk swizzle
// keeps fragment ds_read_b128 conflict-free. Epilogue transposes through LDS
// for full-line dwordx4 key stores.
__global__ __launch_bounds__(256) void gemm_sim_mfma(const unsigned short* __restrict__ Rb,
                                                     const float* __restrict__ sq,
                                                     const int* __restrict__ labels,
                                                     unsigned short* __restrict__ simk) {
    __shared__ unsigned short sAB[32768];   // 64KB: A tile [0,16384), B tile [16384,32768)

    const int tid  = threadIdx.x;
    const int wid  = tid >> 6, lane = tid & 63;
    const int q    = lane >> 4, t = lane & 15;
    const int Ay0  = blockIdx.y * 128;
    const int Bx0  = blockIdx.x * 128;
    const int m0   = (wid >> 1) * 64;       // wave's A-row base within tile
    const int n0   = (wid & 1) * 64;        // wave's B-row base within tile

    // ---- stage: 4096 chunk-slots of 16B; slot s=(r<<4)|p holds global chunk
    // (p ^ (r&15)) of row r  (XOR swizzle; reads below invert it) ----
#pragma unroll
    for (int it = 0; it < 16; ++it) {
        int s = (wid * 16 + it) * 64 + lane;        // 0..4095
        int local = s & 2047;                       // within one 32KB tile
        int r = local >> 4;
        int p = local & 15;
        int srcrow = ((s < 2048) ? Ay0 : Bx0) + r;
        const uint4* src = (const uint4*)(Rb + (size_t)srcrow * D + ((p ^ (r & 15)) << 3));
        *(uint4*)(&sAB[(size_t)s * 8]) = *src;      // ds_write_b128
    }
    __syncthreads();

    f32x4 acc[4][4];
#pragma unroll
    for (int mi = 0; mi < 4; ++mi)
#pragma unroll
        for (int ni = 0; ni < 4; ++ni) acc[mi][ni] = (f32x4)0.0f;

    // ---- MFMA: fragment (row, kchunk kq*4+q) at LDS chunk ((kq*4+q)^t) ----
#pragma unroll
    for (int kq = 0; kq < 4; ++kq) {
        bf16x8 af[4], bfr[4];
        const int ksw = (kq * 4 + q);
#pragma unroll
        for (int mi = 0; mi < 4; ++mi) {
            int r = m0 + mi * 16 + t;
            af[mi] = *(bf16x8*)(&sAB[(size_t)r * 128 + ((ksw ^ t) << 3)]);
        }
#pragma unroll
        for (int ni = 0; ni < 4; ++ni) {
            int r = n0 + ni * 16 + t;
            bfr[ni] = *(bf16x8*)(&sAB[16384 + (size_t)r * 128 + ((ksw ^ t) << 3)]);
        }
#pragma unroll
        for (int mi = 0; mi < 4; ++mi)
#pragma unroll
            for (int ni = 0; ni < 4; ++ni)
                acc[mi][ni] = __builtin_amdgcn_mfma_f32_16x16x32_bf16(
                    af[mi], bfr[ni], acc[mi][ni], 0, 0, 0);
    }

    __syncthreads();   // staging LDS dead; reuse per-wave for epilogue transpose

    // ---- epilogue: keys -> LDS [64 rows][stride 72 ushorts], then coalesced out
    const int epi0 = wid * 4608;            // 64*72 ushorts per wave
    float sqc[4]; int lc[4];
#pragma unroll
    for (int ni = 0; ni < 4; ++ni) {
        sqc[ni] = sq[Bx0 + n0 + ni * 16 + t];
        lc[ni]  = labels[Bx0 + n0 + ni * 16 + t];
    }
#pragma unroll
    for (int mi = 0; mi < 4; ++mi) {
#pragma unroll
        for (int r = 0; r < 4; ++r) {
            int lrow = mi * 16 + q * 4 + r;           // 0..63 within wave tile
            int grow = Ay0 + m0 + lrow;
            float sqr = sq[grow];
            int   lr  = labels[grow];
#pragma unroll
            for (int ni = 0; ni < 4; ++ni) {
                float g  = acc[mi][ni][r];
                float d2 = fmaxf(sqr + sqc[ni] - 2.0f * g, 0.0f);
                float dist = (d2 > 0.0f) ? sqrtf(d2) : 0.0f;
                float s = -dist + ((lr == lc[ni]) ? 0.0f : MARGIN_F);
                uint32_t key = xform_key(s);          // sim <= 0.2 -> no ovf on +0x8000
                sAB[epi0 + lrow * 72 + ni * 16 + t] =
                    (unsigned short)((key + 0x8000u) >> 16);
            }
        }
    }
    // wave-internal ds ordering; compiler inserts lgkmcnt before dependent reads
#pragma unroll
    for (int it = 0; it < 8; ++it) {
        int rr = it * 8 + (lane >> 3);
        int cc = (lane & 7) * 8;
        uint4 v = *(uint4*)(&sAB[epi0 + rr * 72 + cc]);
        *(uint4*)(simk + (size_t)(Ay0 + m0 + rr) * B + Bx0 + n0 + cc) = v;
    }
}

// ONE WAVE PER ROW (unchanged from r6): 64 16-bit keys/lane in 8 uint4.
__global__ __launch_bounds__(256) void row_loss16(const unsigned short* __restrict__ simk,
                                                  const int* __restrict__ labels,
                                                  float* __restrict__ out) {
    __shared__ uint32_t cand_u[4][CW];
    __shared__ int      cand_m[4][CW];
    __shared__ int      cnt_w[4];
    __shared__ float    wsum[4];

    const int wid  = threadIdx.x >> 6;
    const int lane = threadIdx.x & 63;
    const int row  = blockIdx.x * 4 + wid;

    if (lane == 0) cnt_w[wid] = 0;

    const uint4* pv = (const uint4*)(simk + (size_t)row * B);
    const int4*  lv = (const int4*)labels;
    const int li = labels[row];

    uint4 kv[8];
    uint64_t mbits = 0;
    uint32_t t1 = 0, t2 = 0;
#pragma unroll
    for (int q = 0; q < 8; ++q) {
        kv[q] = pv[q * 64 + lane];
        const int lb = (q * 64 + lane) * 2;
        int4 la = lv[lb], lc = lv[lb + 1];
        uint32_t u[8] = {kv[q].x & 0xFFFFu, kv[q].x >> 16,
                         kv[q].y & 0xFFFFu, kv[q].y >> 16,
                         kv[q].z & 0xFFFFu, kv[q].z >> 16,
                         kv[q].w & 0xFFFFu, kv[q].w >> 16};
#pragma unroll
        for (int c = 0; c < 8; ++c) {
            uint32_t mn = min(t1, u[c]);
            t1 = max(t1, u[c]);
            t2 = max(t2, mn);
        }
        mbits |= (uint64_t)(la.x == li) << (q * 8 + 0);
        mbits |= (uint64_t)(la.y == li) << (q * 8 + 1);
        mbits |= (uint64_t)(la.z == li) << (q * 8 + 2);
        mbits |= (uint64_t)(la.w == li) << (q * 8 + 3);
        mbits |= (uint64_t)(lc.x == li) << (q * 8 + 4);
        mbits |= (uint64_t)(lc.y == li) << (q * 8 + 5);
        mbits |= (uint64_t)(lc.z == li) << (q * 8 + 6);
        mbits |= (uint64_t)(lc.w == li) << (q * 8 + 7);
    }

    int kloc = __popcll(mbits);
#pragma unroll
    for (int off = 32; off > 0; off >>= 1) kloc += __shfl_xor(kloc, off);
    const int k = kloc;
    const float kf = (float)k;

    // ballot binary search: T = k-th largest of the 128-subset (<= true k-th)
    const int kneed = min(k, 128);
    uint32_t T = 0;
#pragma unroll
    for (int b = 15; b >= 0; --b) {
        uint32_t g = T | (1u << b);
        int c = __popcll(__ballot(t1 >= g)) + __popcll(__ballot(t2 >= g));
        if (c >= kneed) T = g;
    }

    // gather candidates = {u >= T} U {matches}
#pragma unroll
    for (int q = 0; q < 8; ++q) {
        uint32_t u[8] = {kv[q].x & 0xFFFFu, kv[q].x >> 16,
                         kv[q].y & 0xFFFFu, kv[q].y >> 16,
                         kv[q].z & 0xFFFFu, kv[q].z >> 16,
                         kv[q].w & 0xFFFFu, kv[q].w >> 16};
#pragma unroll
        for (int c = 0; c < 8; ++c) {
            int e = q * 8 + c;
            int m = (int)((mbits >> e) & 1);
            if (u[c] >= T || m) {
                int p = atomicAdd(&cnt_w[wid], 1);
                if (p < CW) {
                    cand_u[wid][p] = u[c];
                    cand_m[wid][p] = ((q * 64 + lane) * 8 + c) | (m << 12);
                }
            }
        }
    }
    const int ncand = min(cnt_w[wid], CW);

    float facc = 0.0f;

    // candidate-internal exact ranks for u >= T
    for (int s = lane; s < ncand; s += 64) {
        uint32_t uc = cand_u[wid][s];
        int meta = cand_m[wid][s];
        int jc = meta & 0xFFF;
        int m  = (meta >> 12) & 1;
        if (uc >= T) {
            int cnt = 0;
            for (int c = 0; c < ncand; ++c) {
                uint32_t u2 = cand_u[wid][c];
                int j2 = cand_m[wid][c] & 0xFFF;
                cnt += (u2 > uc || (u2 == uc && j2 < jc)) ? 1 : 0;
            }
            int rank = 1 + cnt;
            float v = unxform16(uc);
            if (!m && rank <= k)
                facc += v * (0.5f + ((kf - (float)rank + 1.0f) / kf) * 0.5f);
            else if (m && rank > k)
                facc -= v * (0.5f + (((float)rank - kf) / (float)(B - k)) * 0.5f);
        }
    }

    // below-T matches (rank > k guaranteed): exact global rank from registers
    for (int c = 0; c < ncand; ++c) {
        uint32_t uc = cand_u[wid][c];
        if (uc < T) {
            int jc = cand_m[wid][c] & 0xFFF;
            int cnt = 0;
#pragma unroll
            for (int q = 0; q < 8; ++q) {
                uint32_t u[8] = {kv[q].x & 0xFFFFu, kv[q].x >> 16,
                                 kv[q].y & 0xFFFFu, kv[q].y >> 16,
                                 kv[q].z & 0xFFFFu, kv[q].z >> 16,
                                 kv[q].w & 0xFFFFu, kv[q].w >> 16};
                int jb = (q * 64 + lane) * 8;
#pragma unroll
                for (int cc = 0; cc < 8; ++cc)
                    cnt += (u[cc] > uc || (u[cc] == uc && jb + cc < jc)) ? 1 : 0;
            }
#pragma unroll
            for (int off = 32; off > 0; off >>= 1) cnt += __shfl_xor(cnt, off);
            if (lane == 0) {
                int rank = 1 + cnt;
                float v = unxform16(uc);
                facc -= v * (0.5f + (((float)rank - kf) / (float)(B - k)) * 0.5f);
            }
        }
    }

#pragma unroll
    for (int off = 32; off > 0; off >>= 1) facc += __shfl_xor(facc, off);
    if (lane == 0) wsum[wid] = facc;
    __syncthreads();
    if (threadIdx.x == 0)
        atomicAdd(out, wsum[0] + wsum[1] + wsum[2] + wsum[3]);
}

extern "C" void kernel_launch(void* const* d_in, const int* in_sizes, int n_in,
                              void* d_out, int out_size, void* d_ws, size_t ws_size,
                              hipStream_t stream) {
    const float* R      = (const float*)d_in[0];
    const int*   labels = (const int*)d_in[1];
    float* out = (float*)d_out;

    float*          sq   = (float*)d_ws;                                     // 16 KB
    unsigned short* Rb   = (unsigned short*)((char*)d_ws + 16 * 1024);       // 1 MB
    unsigned short* simk = (unsigned short*)((char*)d_ws + 16 * 1024 + 1024 * 1024 + 256);

    hipLaunchKernelGGL(sq_kernel, dim3(B / 4), dim3(256), 0, stream, R, sq, out);
    hipLaunchKernelGGL(conv_kernel, dim3(B * D / 1024), dim3(256), 0, stream, R, Rb);
    hipLaunchKernelGGL(gemm_sim_mfma, dim3(B / 128, B / 128), dim3(256), 0, stream,
                       Rb, sq, labels, simk);
    hipLaunchKernelGGL(row_loss16, dim3(B / 4), dim3(256), 0, stream, simk, labels, out);
}